// Round 4
// baseline (84.241 us; speedup 1.0000x reference)
//
#include <hip/hip_runtime.h>
#include <math.h>

// Problem constants (reference: pos [64,1024,3] fp32, rad=0.15)
#define TN     64
#define NP     1024
#define RADIUS 0.15f
#define MIN_D  (2.0f * RADIUS)
#define R2     (MIN_D * MIN_D)

#define SPLIT  16                  // blocks per timestep -> 1024 blocks = 4/CU, one round
#define GI     16                  // i-rows register-tiled per j sweep
#define NGRP   (NP / GI)           // 64 groups per timestep
#define GPB    (NGRP / SPLIT)      // 4 groups per block
#define BLOCK  256
#define NBLK   (TN * SPLIT)        // 1024 blocks

__launch_bounds__(BLOCK, 4)   // cap 128 VGPR: i-tile stays resident, no remat from LDS
__global__ void collide_kernel(const float* __restrict__ pos,
                               float* __restrict__ partial) {
    // interleaved x,y,z layout: hot-loop reads sh[3j+c] -> 2 lanes/bank (free);
    // lets us stage with float4 -> ds_write_b128 (no unpack math)
    __shared__ float sh[NP * 3];
    const int t     = blockIdx.x / SPLIT;
    const int split = blockIdx.x % SPLIT;
    const int tid   = threadIdx.x;

    const float4* p4  = (const float4*)(pos + (size_t)t * NP * 3);
    float4*       sh4 = (float4*)sh;
    #pragma unroll
    for (int i = 0; i < (NP * 3 / 4) / BLOCK; ++i)     // 3 iters
        sh4[tid + i * BLOCK] = p4[tid + i * BLOCK];
    __syncthreads();

    float cnt  = 0.0f;   // exact in fp32 (< 2^24)
    float loss = 0.0f;

    #pragma unroll
    for (int m = 0; m < GPB; ++m) {
        // snake: pair m even/odd uses split and (SPLIT-1-split) so per-block
        // total tail length is constant -> perfect load balance
        const int g = (m & 1) ? (m * SPLIT + (SPLIT - 1 - split))
                              : (m * SPLIT + split);
        const int b = g * GI;

        float xi[GI], yi[GI], zi[GI];
        #pragma unroll
        for (int k = 0; k < GI; ++k) {                 // wave-uniform -> LDS broadcast
            xi[k] = sh[3 * (b + k) + 0];
            yi[k] = sh[3 * (b + k) + 1];
            zi[k] = sh[3 * (b + k) + 2];
        }

        // head: in-group pairs, j in (b, b+GI), one lane per j (first wave only)
        if (tid < GI - 1) {
            const int j = b + 1 + tid;
            const float xj = sh[3 * j], yj = sh[3 * j + 1], zj = sh[3 * j + 2];
            #pragma unroll
            for (int k = 0; k < GI; ++k) {
                if (k <= tid) {                        // i = b+k < j
                    const float dx = xi[k] - xj;
                    const float dy = yi[k] - yj;
                    const float dz = zi[k] - zj;
                    const float d2 = dx * dx + dy * dy + dz * dz;
                    if (d2 < R2) {
                        cnt += 1.0f;
                        const float pen = MIN_D - sqrtf(d2);
                        loss += pen * pen;
                    }
                }
            }
        }

        // tail: j >= b+GI, all GI i-rows valid — branchless count, guarded sqrt
        #pragma unroll 1
        for (int j = b + GI + tid; j < NP; j += BLOCK) {
            const float xj = sh[3 * j], yj = sh[3 * j + 1], zj = sh[3 * j + 2];
            #pragma unroll
            for (int k = 0; k < GI; ++k) {
                const float dx = xi[k] - xj;
                const float dy = yi[k] - yj;
                const float dz = zi[k] - zj;
                const float d2 = dx * dx + dy * dy + dz * dz;
                const bool hit = d2 < R2;
                cnt += hit ? 1.0f : 0.0f;              // v_cmp + cndmask+add, no branch
                if (hit) {                             // rare (~0.25% of pairs): sqrt only here
                    const float pen = MIN_D - sqrtf(d2);
                    loss += pen * pen;
                }
            }
        }
    }

    // wave (64-lane) reduction, then cross-wave via LDS
    #pragma unroll
    for (int off = 32; off > 0; off >>= 1) {
        cnt  += __shfl_down(cnt, off);
        loss += __shfl_down(loss, off);
    }
    __shared__ float cs[BLOCK / 64], ls[BLOCK / 64];
    const int wave = tid >> 6;
    if ((tid & 63) == 0) { cs[wave] = cnt; ls[wave] = loss; }
    __syncthreads();
    if (tid == 0) {
        float c = 0.0f, l = 0.0f;
        #pragma unroll
        for (int w = 0; w < BLOCK / 64; ++w) { c += cs[w]; l += ls[w]; }
        partial[2 * blockIdx.x + 0] = c;   // unconditional store every launch: no init needed
        partial[2 * blockIdx.x + 1] = l;
    }
}

__global__ void finalize_kernel(const float* __restrict__ partial,
                                float* __restrict__ out) {
    const int tid = threadIdx.x;
    float c = 0.0f, l = 0.0f;
    #pragma unroll
    for (int i = 0; i < NBLK / BLOCK; ++i) {           // 4 float2 per thread
        const float2 p = ((const float2*)partial)[tid + i * BLOCK];
        c += p.x;
        l += p.y;
    }
    #pragma unroll
    for (int off = 32; off > 0; off >>= 1) {
        c += __shfl_down(c, off);
        l += __shfl_down(l, off);
    }
    __shared__ float cs[BLOCK / 64], ls[BLOCK / 64];
    const int wave = tid >> 6;
    if ((tid & 63) == 0) { cs[wave] = c; ls[wave] = l; }
    __syncthreads();
    if (tid == 0) {
        float ct = 0.0f, lt = 0.0f;
        #pragma unroll
        for (int w = 0; w < BLOCK / 64; ++w) { ct += cs[w]; lt += ls[w]; }
        out[0] = ct;   // harness reads d_out as float32; count exact (< 2^24)
        out[1] = lt;
    }
}

extern "C" void kernel_launch(void* const* d_in, const int* in_sizes, int n_in,
                              void* d_out, int out_size, void* d_ws, size_t ws_size,
                              hipStream_t stream) {
    const float* pos     = (const float*)d_in[0];
    float*       partial = (float*)d_ws;
    float*       out     = (float*)d_out;

    collide_kernel<<<NBLK, BLOCK, 0, stream>>>(pos, partial);
    finalize_kernel<<<1, BLOCK, 0, stream>>>(partial, out);
}

// Round 5
// 72.782 us; speedup vs baseline: 1.1574x; 1.1574x over previous
//
#include <hip/hip_runtime.h>
#include <math.h>

// Problem constants (reference: pos [64,1024,3] fp32, rad=0.15)
#define TN     64
#define NP     1024
#define RADIUS 0.15f
#define MIN_D  (2.0f * RADIUS)
#define R2     (MIN_D * MIN_D)

#define SPLIT  16                  // blocks per timestep -> 1024 blocks = 4/CU, one round
#define GI     16                  // i-rows register-tiled per j sweep
#define NGRP   (NP / GI)           // 64 groups per timestep
#define GPB    (NGRP / SPLIT)      // 4 groups per block
#define BLOCK  256
#define NBLK   (TN * SPLIT)        // 1024 blocks

__launch_bounds__(BLOCK, 4)   // allow up to 128 VGPR (4 waves/EU)
__global__ void collide_kernel(const float* __restrict__ pos,
                               float* __restrict__ partial) {
    // interleaved x,y,z: float4 staging, stride-3 j-reads = 2 lanes/bank (free)
    __shared__ float sh[NP * 3];
    const int t     = blockIdx.x / SPLIT;
    const int split = blockIdx.x % SPLIT;
    const int tid   = threadIdx.x;

    const float4* p4  = (const float4*)(pos + (size_t)t * NP * 3);
    float4*       sh4 = (float4*)sh;
    #pragma unroll
    for (int i = 0; i < (NP * 3 / 4) / BLOCK; ++i)     // 3 iters
        sh4[tid + i * BLOCK] = p4[tid + i * BLOCK];
    __syncthreads();

    unsigned int cnt = 0;     // v_cmp + addc per pair
    float loss = 0.0f;

    #pragma unroll
    for (int m = 0; m < GPB; ++m) {
        // snake: per-block total tail length constant -> perfect load balance
        const int g = (m & 1) ? (m * SPLIT + (SPLIT - 1 - split))
                              : (m * SPLIT + split);
        const int b = g * GI;

        float xi[GI], yi[GI], zi[GI];
        #pragma unroll
        for (int k = 0; k < GI; ++k) {
            xi[k] = sh[3 * (b + k) + 0];
            yi[k] = sh[3 * (b + k) + 1];
            zi[k] = sh[3 * (b + k) + 2];
        }
        // Opaque compiler barrier: pins the 48-value i-tile into VGPRs and makes
        // rematerialization from LDS impossible. Without this the allocator
        // re-reads LDS per j-iteration to minimize VGPRs (observed: VGPR=32,
        // ~56 lane-ops/pair instead of ~9).
        #pragma unroll
        for (int k = 0; k < GI; ++k)
            asm volatile("" : "+v"(xi[k]), "+v"(yi[k]), "+v"(zi[k]));

        // head: in-group pairs, j in (b, b+GI), one lane per j (first wave only)
        if (tid < GI - 1) {
            const int j = b + 1 + tid;
            const float xj = sh[3 * j], yj = sh[3 * j + 1], zj = sh[3 * j + 2];
            #pragma unroll
            for (int k = 0; k < GI; ++k) {
                if (k <= tid) {                        // i = b+k < j
                    const float dx = xi[k] - xj;
                    const float dy = yi[k] - yj;
                    const float dz = zi[k] - zj;
                    const float d2 = dx * dx + dy * dy + dz * dz;
                    if (d2 < R2) {
                        cnt++;
                        const float pen = MIN_D - __builtin_amdgcn_sqrtf(d2);
                        loss += pen * pen;
                    }
                }
            }
        }

        // tail: j >= b+GI, all GI i-rows valid
        for (int j = b + GI + tid; j < NP; j += BLOCK) {
            const float xj = sh[3 * j], yj = sh[3 * j + 1], zj = sh[3 * j + 2];
            #pragma unroll
            for (int k = 0; k < GI; ++k) {
                const float dx = xi[k] - xj;
                const float dy = yi[k] - yj;
                const float dz = zi[k] - zj;
                const float d2 = dx * dx + dy * dy + dz * dz;
                const bool hit = d2 < R2;
                cnt += hit ? 1u : 0u;                  // v_cmp + v_addc, no branch
                if (hit) {                             // rare (~0.25%): sqrt only here
                    const float pen = MIN_D - __builtin_amdgcn_sqrtf(d2);
                    loss += pen * pen;
                }
            }
        }
    }

    // wave (64-lane) reduction, then cross-wave via LDS
    float fcnt = (float)cnt;
    #pragma unroll
    for (int off = 32; off > 0; off >>= 1) {
        fcnt += __shfl_down(fcnt, off);
        loss += __shfl_down(loss, off);
    }
    __shared__ float cs[BLOCK / 64], ls[BLOCK / 64];
    const int wave = tid >> 6;
    if ((tid & 63) == 0) { cs[wave] = fcnt; ls[wave] = loss; }
    __syncthreads();
    if (tid == 0) {
        float c = 0.0f, l = 0.0f;
        #pragma unroll
        for (int w = 0; w < BLOCK / 64; ++w) { c += cs[w]; l += ls[w]; }
        partial[2 * blockIdx.x + 0] = c;   // unconditional store: no init kernel needed
        partial[2 * blockIdx.x + 1] = l;
    }
}

__global__ void finalize_kernel(const float* __restrict__ partial,
                                float* __restrict__ out) {
    const int tid = threadIdx.x;
    float c = 0.0f, l = 0.0f;
    #pragma unroll
    for (int i = 0; i < NBLK / BLOCK; ++i) {           // 4 float2 per thread
        const float2 p = ((const float2*)partial)[tid + i * BLOCK];
        c += p.x;
        l += p.y;
    }
    #pragma unroll
    for (int off = 32; off > 0; off >>= 1) {
        c += __shfl_down(c, off);
        l += __shfl_down(l, off);
    }
    __shared__ float cs[BLOCK / 64], ls[BLOCK / 64];
    const int wave = tid >> 6;
    if ((tid & 63) == 0) { cs[wave] = c; ls[wave] = l; }
    __syncthreads();
    if (tid == 0) {
        float ct = 0.0f, lt = 0.0f;
        #pragma unroll
        for (int w = 0; w < BLOCK / 64; ++w) { ct += cs[w]; lt += ls[w]; }
        out[0] = ct;   // harness reads d_out as float32; count exact (< 2^24)
        out[1] = lt;
    }
}

extern "C" void kernel_launch(void* const* d_in, const int* in_sizes, int n_in,
                              void* d_out, int out_size, void* d_ws, size_t ws_size,
                              hipStream_t stream) {
    const float* pos     = (const float*)d_in[0];
    float*       partial = (float*)d_ws;
    float*       out     = (float*)d_out;

    collide_kernel<<<NBLK, BLOCK, 0, stream>>>(pos, partial);
    finalize_kernel<<<1, BLOCK, 0, stream>>>(partial, out);
}